// Round 1
// baseline (1505.766 us; speedup 1.0000x reference)
//
#include <hip/hip_runtime.h>
#include <hip/hip_bf16.h>

typedef __attribute__((ext_vector_type(8))) short short8;
typedef __attribute__((ext_vector_type(4))) float f32x4;

#define BATCH 16
#define CI 512
#define CO 512
#define HW 64
#define SD 512
#define PAD 66   // 64 + 2 halo
#define NCH 16   // channel chunks of 32

// sizes (elements)
#define S_SZ     (BATCH*CI)                 // style proj result
#define WSQ_SZ   (CO*CI)
#define WT_SZ    (9*CO*CI)
#define WB_PER_B ((size_t)9*NCH*CO*32)      // 2,359,296 shorts
#define XB_PER_B ((size_t)NCH*PAD*PAD*32)   // 2,227,200 shorts

static __device__ __forceinline__ short f2bf(float v) {
    unsigned u = __float_as_uint(v);
    unsigned r = (u + 0x7fffu + ((u >> 16) & 1u)) >> 16;
    return (short)r;
}

// ---------------- K1: s[b][c] = style[b] . proj_w[c] + proj_b[c] ----------------
__global__ void k_style(const float* __restrict__ style, const float* __restrict__ proj_w,
                        const float* __restrict__ proj_b, float* __restrict__ s) {
    int b = blockIdx.x;
    __shared__ float st[SD];
    for (int d = threadIdx.x; d < SD; d += 256) st[d] = style[b*SD + d];
    __syncthreads();
    for (int c = threadIdx.x; c < CI; c += 256) {
        const float4* pw4 = reinterpret_cast<const float4*>(proj_w + (size_t)c*SD);
        float sum = 0.f;
        for (int d4 = 0; d4 < SD/4; ++d4) {
            float4 v = pw4[d4];
            sum += v.x*st[d4*4] + v.y*st[d4*4+1] + v.z*st[d4*4+2] + v.w*st[d4*4+3];
        }
        s[b*CI + c] = sum + proj_b[c];
    }
}

// ------------- K2: wsq[o][i] = sum_t w^2 ; wt[t][o][i] = weight[o][i][t] -------------
__global__ void k_wprep(const float* __restrict__ weight, float* __restrict__ wsq,
                        float* __restrict__ wt) {
    int o = blockIdx.x;
    for (int i = threadIdx.x; i < CI; i += 256) {
        const float* wp = weight + ((size_t)o*CI + i)*9;
        float sq = 0.f;
        #pragma unroll
        for (int t = 0; t < 9; ++t) {
            float v = wp[t];
            sq += v*v;
            wt[((size_t)t*CO + o)*CI + i] = v;
        }
        wsq[o*CI + i] = sq;
    }
}

// ------------- K3: demod[b][o] = rsqrt(sum_i s^2 * wsq + 1e-8) -------------
__global__ void k_demod(const float* __restrict__ s, const float* __restrict__ wsq,
                        float* __restrict__ demod) {
    int b = blockIdx.x;
    __shared__ float s2[CI];
    for (int d = threadIdx.x; d < CI; d += 256) { float v = s[b*CI + d]; s2[d] = v*v; }
    __syncthreads();
    for (int o = threadIdx.x; o < CO; o += 256) {
        const float4* wq4 = reinterpret_cast<const float4*>(wsq + (size_t)o*CI);
        float sum = 1e-8f;
        for (int d4 = 0; d4 < CI/4; ++d4) {
            float4 v = wq4[d4];
            sum += v.x*s2[d4*4] + v.y*s2[d4*4+1] + v.z*s2[d4*4+2] + v.w*s2[d4*4+3];
        }
        demod[b*CO + o] = rsqrtf(sum);
    }
}

// ------------- K4: wb[b][t][chunk][o][i32] = bf16(wt * s * demod) -------------
__global__ void k_wbfill(const float* __restrict__ wt, const float* __restrict__ s,
                         const float* __restrict__ demod, short* __restrict__ wb) {
    int b = blockIdx.x, t = blockIdx.y, ch = blockIdx.z;
    const float* wtp = wt + (size_t)t*CO*CI;
    short* outp = wb + (size_t)b*WB_PER_B + (((size_t)t*NCH + ch)*CO)*32;
    for (int u = threadIdx.x; u < CO*4; u += 256) {
        int o = u >> 2, q = u & 3;
        int i0 = ch*32 + q*8;
        float dm = demod[b*CO + o];
        const float* wrow = wtp + (size_t)o*CI + i0;
        const float* srow = s + b*CI + i0;
        short8 r;
        #pragma unroll
        for (int j = 0; j < 8; ++j) r[j] = f2bf(wrow[j] * srow[j] * dm);
        *reinterpret_cast<short8*>(outp + o*32 + q*8) = r;
    }
}

// ------------- K5: xb[b][chunk][r][c][ch32] = bf16(x padded) -------------
__global__ void k_xbfill(const float* __restrict__ x, short* __restrict__ xb) {
    int r = blockIdx.x, ch = blockIdx.y, b = blockIdx.z;
    short* outp = xb + (size_t)b*XB_PER_B + (((size_t)ch*PAD + r)*PAD)*32;
    for (int e = threadIdx.x; e < PAD*32; e += 64) {
        int c = e >> 5, cc = e & 31;
        float v = 0.f;
        if (r >= 1 && r <= HW && c >= 1 && c <= HW)
            v = x[(((size_t)b*CI + ch*32 + cc)*HW + (r-1))*HW + (c-1)];
        outp[e] = f2bf(v);
    }
}

// ------------- K6: conv via implicit GEMM, mfma 16x16x32 bf16 -------------
// block: (b, ot in 0..3, pt in 0..31); 4 waves 2x2; wave = 64 o x one 64-px row
__global__ __launch_bounds__(256) void k_conv(
        const short* __restrict__ wb, const short* __restrict__ xb,
        const float* __restrict__ noise, const float* __restrict__ noise_strength,
        const float* __restrict__ bias, float* __restrict__ out) {
    int raw = blockIdx.x;
    int bid = (raw & 7) * 256 + (raw >> 3);   // XCD swizzle (2048 % 8 == 0)
    int b  = bid >> 7;
    int rem = bid & 127;
    int ot = rem >> 5;
    int pt = rem & 31;

    int tid  = threadIdx.x;
    int lane = tid & 63;
    int wid  = tid >> 6;
    int wr = wid >> 1, wc = wid & 1;
    int n16 = lane & 15, kb = lane >> 4;

    int h = pt*2 + wc;               // output row for this wave
    int obase = ot*128 + wr*64;      // first output channel of this wave

    const short* wT = wb + (size_t)b*WB_PER_B + (obase + n16)*32 + kb*8;
    const short* xT = xb + (size_t)b*XB_PER_B + n16*32 + kb*8;

    f32x4 acc[4][4] = {};

    for (int ch = 0; ch < NCH; ++ch) {
        const short* wC = wT + ch*(CO*32);
        const short* xC = xT + ch*(PAD*PAD*32);
        #pragma unroll
        for (int dh = 0; dh < 3; ++dh) {
            const short* xrow = xC + (h + dh)*(PAD*32);
            #pragma unroll
            for (int dw = 0; dw < 3; ++dw) {
                const short* wtap = wC + (dh*3 + dw)*(NCH*CO*32);
                short8 a[4], bb[4];
                #pragma unroll
                for (int am = 0; am < 4; ++am)
                    a[am] = *reinterpret_cast<const short8*>(wtap + am*16*32);
                #pragma unroll
                for (int an = 0; an < 4; ++an)
                    bb[an] = *reinterpret_cast<const short8*>(xrow + (an*16 + dw)*32);
                #pragma unroll
                for (int am = 0; am < 4; ++am)
                    #pragma unroll
                    for (int an = 0; an < 4; ++an)
                        acc[am][an] = __builtin_amdgcn_mfma_f32_16x16x32_bf16(
                            a[am], bb[an], acc[am][an], 0, 0, 0);
            }
        }
    }

    // epilogue: + noise*strength + bias
    float ns0 = noise_strength[0];
    const float* nz = noise + b*HW*HW + h*HW + n16;
    float* ob = out + ((size_t)b*CO + obase)*HW*HW + h*HW + n16;
    #pragma unroll
    for (int an = 0; an < 4; ++an) {
        float nv = nz[an*16] * ns0;
        #pragma unroll
        for (int am = 0; am < 4; ++am) {
            int o_lo = am*16 + kb*4;
            #pragma unroll
            for (int j = 0; j < 4; ++j) {
                float bv = bias[obase + o_lo + j];
                ob[(size_t)(o_lo + j)*(HW*HW) + an*16] = acc[am][an][j] + nv + bv;
            }
        }
    }
}

extern "C" void kernel_launch(void* const* d_in, const int* in_sizes, int n_in,
                              void* d_out, int out_size, void* d_ws, size_t ws_size,
                              hipStream_t stream) {
    const float* x        = (const float*)d_in[0];
    const float* style    = (const float*)d_in[1];
    const float* noise    = (const float*)d_in[2];
    const float* weight   = (const float*)d_in[3];
    const float* proj_w   = (const float*)d_in[4];
    const float* proj_b   = (const float*)d_in[5];
    const float* noise_st = (const float*)d_in[6];
    const float* bias     = (const float*)d_in[7];
    float* out = (float*)d_out;

    // workspace partition
    float* s     = (float*)d_ws;               // 16*512
    float* demod = s + S_SZ;                   // 16*512
    float* wsq   = demod + S_SZ;               // 512*512
    float* wt    = wsq + WSQ_SZ;               // 9*512*512
    short* wbuf  = (short*)(wt + WT_SZ);       // 16 * 2,359,296
    short* xbuf  = wbuf + BATCH*WB_PER_B;      // 16 * 2,227,200

    k_style<<<BATCH, 256, 0, stream>>>(style, proj_w, proj_b, s);
    k_wprep<<<CO, 256, 0, stream>>>(weight, wsq, wt);
    k_demod<<<BATCH, 256, 0, stream>>>(s, wsq, demod);
    k_wbfill<<<dim3(BATCH, 9, NCH), 256, 0, stream>>>(wt, s, demod, wbuf);
    k_xbfill<<<dim3(PAD, NCH, BATCH), 64, 0, stream>>>(x, xbuf);
    k_conv<<<2048, 256, 0, stream>>>(wbuf, xbuf, noise, noise_st, bias, out);
}

// Round 3
// 691.371 us; speedup vs baseline: 2.1779x; 2.1779x over previous
//
#include <hip/hip_runtime.h>
#include <hip/hip_bf16.h>

typedef __attribute__((ext_vector_type(8))) short short8;
typedef __attribute__((ext_vector_type(4))) float f32x4;
typedef unsigned int u32;

#define BATCH 16
#define CI 512
#define CO 512
#define HW 64
#define SD 512
#define PAD 66   // 64 + 2 halo
#define NCH 16   // channel chunks of 32
#define NK  144  // 16 chunks * 9 taps

// sizes (elements)
#define S_SZ     (BATCH*CI)
#define WSQ_SZ   (CO*CI)
#define WT_SZ    (9*CO*CI)
#define WB_PER_B ((size_t)9*NCH*CO*32)      // shorts
#define XB_PER_B ((size_t)NCH*PAD*PAD*32)   // shorts
#define XROW (PAD*32)
#define XCH  (PAD*PAD*32)

static __device__ __forceinline__ short f2bf(float v) {
    unsigned u = __float_as_uint(v);
    unsigned r = (u + 0x7fffu + ((u >> 16) & 1u)) >> 16;
    return (short)r;
}

static __device__ __forceinline__ void async16(const short* g, short* l) {
    __builtin_amdgcn_global_load_lds(
        (const __attribute__((address_space(1))) u32*)g,
        (__attribute__((address_space(3))) u32*)l, 16, 0, 0);
}

// ---------------- K1: s[b][c] = style[b] . proj_w[c] + proj_b[c] ----------------
__global__ void k_style(const float* __restrict__ style, const float* __restrict__ proj_w,
                        const float* __restrict__ proj_b, float* __restrict__ s) {
    int b = blockIdx.x, cs = blockIdx.y;
    __shared__ float st[SD];
    int t = threadIdx.x;
    for (int d = t; d < SD; d += 256) st[d] = style[b*SD + d];
    __syncthreads();
    int cl = t >> 3, g = t & 7;
    int c = cs*32 + cl;
    const float4* pw4 = reinterpret_cast<const float4*>(proj_w + (size_t)c*SD);
    float sum = 0.f;
    #pragma unroll
    for (int it = 0; it < 16; ++it) {
        float4 v = pw4[g + it*8];
        int d0 = (g + it*8)*4;
        sum += v.x*st[d0] + v.y*st[d0+1] + v.z*st[d0+2] + v.w*st[d0+3];
    }
    sum += __shfl_down(sum, 4);
    sum += __shfl_down(sum, 2);
    sum += __shfl_down(sum, 1);
    if (g == 0) s[b*CI + c] = sum + proj_b[c];
}

// ------------- K2: wsq[o][i] = sum_t w^2 ; wt[t][o][i] = weight[o][i][t] -------------
__global__ void k_wprep(const float* __restrict__ weight, float* __restrict__ wsq,
                        float* __restrict__ wt) {
    int o = blockIdx.x;
    for (int i = threadIdx.x; i < CI; i += 256) {
        const float* wp = weight + ((size_t)o*CI + i)*9;
        float sq = 0.f;
        #pragma unroll
        for (int t = 0; t < 9; ++t) {
            float v = wp[t];
            sq += v*v;
            wt[((size_t)t*CO + o)*CI + i] = v;
        }
        wsq[o*CI + i] = sq;
    }
}

// ------------- K3: demod[b][o] = rsqrt(sum_i s^2 * wsq + 1e-8) -------------
__global__ void k_demod(const float* __restrict__ s, const float* __restrict__ wsq,
                        float* __restrict__ demod) {
    int b = blockIdx.x, os = blockIdx.y;
    __shared__ float s2[CI];
    int t = threadIdx.x;
    for (int d = t; d < CI; d += 256) { float v = s[b*CI + d]; s2[d] = v*v; }
    __syncthreads();
    int ol = t >> 3, g = t & 7;
    int o = os*32 + ol;
    const float4* wq4 = reinterpret_cast<const float4*>(wsq + (size_t)o*CI);
    float sum = 1e-8f;
    #pragma unroll
    for (int it = 0; it < 16; ++it) {
        float4 v = wq4[g + it*8];
        int d0 = (g + it*8)*4;
        sum += v.x*s2[d0] + v.y*s2[d0+1] + v.z*s2[d0+2] + v.w*s2[d0+3];
    }
    sum += __shfl_down(sum, 4);
    sum += __shfl_down(sum, 2);
    sum += __shfl_down(sum, 1);
    if (g == 0) demod[b*CO + o] = rsqrtf(sum);
}

// ------------- K4: wb[b][t][chunk][o][i32] = bf16(wt * s * demod) -------------
__global__ void k_wbfill(const float* __restrict__ wt, const float* __restrict__ s,
                         const float* __restrict__ demod, short* __restrict__ wb) {
    int b = blockIdx.x, t = blockIdx.y, ch = blockIdx.z;
    short* outp = wb + (size_t)b*WB_PER_B + (((size_t)t*NCH + ch)*CO)*32;
    for (int u = threadIdx.x; u < CO*4; u += 256) {
        int o = u >> 2, q = u & 3;
        int i0 = ch*32 + q*8;
        float dm = demod[b*CO + o];
        const float4* wrow = reinterpret_cast<const float4*>(wt + (size_t)t*CO*CI + (size_t)o*CI + i0);
        const float4* srow = reinterpret_cast<const float4*>(s + b*CI + i0);
        float4 w0 = wrow[0], w1 = wrow[1], s0 = srow[0], s1 = srow[1];
        short8 r;
        r[0] = f2bf(w0.x*s0.x*dm); r[1] = f2bf(w0.y*s0.y*dm);
        r[2] = f2bf(w0.z*s0.z*dm); r[3] = f2bf(w0.w*s0.w*dm);
        r[4] = f2bf(w1.x*s1.x*dm); r[5] = f2bf(w1.y*s1.y*dm);
        r[6] = f2bf(w1.z*s1.z*dm); r[7] = f2bf(w1.w*s1.w*dm);
        *reinterpret_cast<short8*>(outp + o*32 + q*8) = r;
    }
}

// ------------- K5: xb[b][chunk][rd][c][ch32] = bf16(x padded), coalesced -------------
__global__ void k_xbfill(const float* __restrict__ x, short* __restrict__ xb) {
    int rd = blockIdx.x;      // dest row 0..65
    int ch = blockIdx.y, b = blockIdx.z;
    int t = threadIdx.x;
    short* rowbase = xb + (size_t)b*XB_PER_B + ((size_t)ch*PAD + rd)*XROW;
    short8 zero = {};
    if (rd == 0 || rd == PAD-1) {
        for (int e = t; e < XROW/8; e += 256)
            *reinterpret_cast<short8*>(rowbase + e*8) = zero;
        return;
    }
    int r = rd - 1;
    __shared__ float tile[32][HW+1];
    int cl = t >> 3, w8 = (t & 7) * 8;
    const float4* src = reinterpret_cast<const float4*>(
        x + (((size_t)(b*CI + ch*32 + cl))*HW + r)*HW + w8);
    float4 v0 = src[0], v1 = src[1];
    tile[cl][w8+0]=v0.x; tile[cl][w8+1]=v0.y; tile[cl][w8+2]=v0.z; tile[cl][w8+3]=v0.w;
    tile[cl][w8+4]=v1.x; tile[cl][w8+5]=v1.y; tile[cl][w8+6]=v1.z; tile[cl][w8+7]=v1.w;
    __syncthreads();
    int w = t >> 2, q = (t & 3) * 8;
    short8 rv;
    #pragma unroll
    for (int j = 0; j < 8; ++j) rv[j] = f2bf(tile[q+j][w]);
    *reinterpret_cast<short8*>(rowbase + (w+1)*32 + q) = rv;
    if (t < 8) {   // zero halo cols 0 and 65
        int px = (t < 4) ? 0 : (PAD-1);
        int qq = (t & 3) * 8;
        *reinterpret_cast<short8*>(rowbase + px*32 + qq) = zero;
    }
}

// ------------- K6: conv as LDS-staged implicit GEMM (m97 structure) -------------
// block: (b, ot 0..3, pt 0..31); 4 waves 2x2; wave = 64 o x 64 px (one row)
__global__ __launch_bounds__(256) void k_conv(
        const short* __restrict__ wb, const short* __restrict__ xb,
        const float* __restrict__ noise, const float* __restrict__ noise_strength,
        const float* __restrict__ bias, float* __restrict__ out) {
    __shared__ short abuf[2][128*32];
    __shared__ short bbuf[2][128*32];

    int raw = blockIdx.x;
    int bid = (raw & 7) * 256 + (raw >> 3);   // XCD swizzle (2048 % 8 == 0)
    int b  = bid >> 7;
    int rem = bid & 127;
    int ot = rem >> 5;
    int pt = rem & 31;

    int tid  = threadIdx.x;
    int lane = tid & 63;
    int wid  = tid >> 6;
    int wr = wid >> 1, wc = wid & 1;
    int n16 = lane & 15, kb = lane >> 4;

    int h0 = pt*2;
    int obase_blk = ot*128;
    int obase = obase_blk + wr*64;

    const short* wbase = wb + (size_t)b*WB_PER_B + (size_t)obase_blk*32;
    const short* xbase = xb + (size_t)b*XB_PER_B;

    // staging: wave wid handles A segs {2wid,2wid+1} and B segs {2wid,2wid+1}
    int sa0 = 2*wid;               // A segment
    int sb0 = 2*wid;               // B segment: hr = s>>2, part = s&3
    int lane8 = lane*8;            // shorts

    f32x4 acc[4][4] = {};

    // stage(buf, ch, dh, dw)
    auto stage = [&](int buf, int ch, int dh, int dw) {
        const short* asrc = wbase + (((size_t)(dh*3+dw)*NCH + ch)*CO)*32;
        async16(asrc +  sa0   *512 + lane8, &abuf[buf][ sa0   *512 + lane8]);
        async16(asrc + (sa0+1)*512 + lane8, &abuf[buf][(sa0+1)*512 + lane8]);
        #pragma unroll
        for (int u = 0; u < 2; ++u) {
            int s = sb0 + u;
            int hr = s >> 2, part = s & 3;
            const short* bsrc = xbase + (size_t)ch*XCH + (size_t)(h0 + hr + dh)*XROW + dw*32;
            async16(bsrc + part*512 + lane8, &bbuf[buf][s*512 + lane8]);
        }
    };

    int ch_n = 0, dh_n = 0, dw_n = 0;
    stage(0, 0, 0, 0);
    // advance
    dw_n = 1;

    int aoff = (wr*64 + n16)*32 + kb*8;
    int boff = (wc*64 + n16)*32 + kb*8;

    for (int kt = 0; kt < NK; ++kt) {
        int cur = kt & 1;
        if (kt + 1 < NK) {
            stage(cur ^ 1, ch_n, dh_n, dw_n);
            if (++dw_n == 3) { dw_n = 0; if (++dh_n == 3) { dh_n = 0; ++ch_n; } }
        }
        __syncthreads();
        const short* A = &abuf[cur][aoff];
        const short* B = &bbuf[cur][boff];
        short8 af[4], bf[4];
        #pragma unroll
        for (int am = 0; am < 4; ++am)
            af[am] = *reinterpret_cast<const short8*>(A + am*16*32);
        #pragma unroll
        for (int an = 0; an < 4; ++an)
            bf[an] = *reinterpret_cast<const short8*>(B + an*16*32);
        #pragma unroll
        for (int am = 0; am < 4; ++am)
            #pragma unroll
            for (int an = 0; an < 4; ++an)
                acc[am][an] = __builtin_amdgcn_mfma_f32_16x16x32_bf16(
                    af[am], bf[an], acc[am][an], 0, 0, 0);
        __syncthreads();
    }

    // epilogue: + noise*strength + bias
    int h = h0 + wc;
    float ns0 = noise_strength[0];
    const float* nz = noise + b*HW*HW + h*HW + n16;
    float* ob = out + ((size_t)b*CO + obase)*HW*HW + h*HW + n16;
    #pragma unroll
    for (int an = 0; an < 4; ++an) {
        float nv = nz[an*16] * ns0;
        #pragma unroll
        for (int am = 0; am < 4; ++am) {
            int o_lo = am*16 + kb*4;
            #pragma unroll
            for (int j = 0; j < 4; ++j) {
                float bv = bias[obase + o_lo + j];
                ob[(size_t)(o_lo + j)*(HW*HW) + an*16] = acc[am][an][j] + nv + bv;
            }
        }
    }
}

extern "C" void kernel_launch(void* const* d_in, const int* in_sizes, int n_in,
                              void* d_out, int out_size, void* d_ws, size_t ws_size,
                              hipStream_t stream) {
    const float* x        = (const float*)d_in[0];
    const float* style    = (const float*)d_in[1];
    const float* noise    = (const float*)d_in[2];
    const float* weight   = (const float*)d_in[3];
    const float* proj_w   = (const float*)d_in[4];
    const float* proj_b   = (const float*)d_in[5];
    const float* noise_st = (const float*)d_in[6];
    const float* bias     = (const float*)d_in[7];
    float* out = (float*)d_out;

    float* s     = (float*)d_ws;
    float* demod = s + S_SZ;
    float* wsq   = demod + S_SZ;
    float* wt    = wsq + WSQ_SZ;
    short* wbuf  = (short*)(wt + WT_SZ);
    short* xbuf  = wbuf + BATCH*WB_PER_B;

    k_style<<<dim3(BATCH, 16), 256, 0, stream>>>(style, proj_w, proj_b, s);
    k_wprep<<<CO, 256, 0, stream>>>(weight, wsq, wt);
    k_demod<<<dim3(BATCH, 16), 256, 0, stream>>>(s, wsq, demod);
    k_wbfill<<<dim3(BATCH, 9, NCH), 256, 0, stream>>>(wt, s, demod, wbuf);
    k_xbfill<<<dim3(PAD, NCH, BATCH), 256, 0, stream>>>(x, xbuf);
    k_conv<<<2048, 256, 0, stream>>>(wbuf, xbuf, noise, noise_st, bias, out);
}

// Round 4
// 679.317 us; speedup vs baseline: 2.2166x; 1.0177x over previous
//
#include <hip/hip_runtime.h>
#include <hip/hip_bf16.h>

typedef __attribute__((ext_vector_type(8))) short short8;
typedef __attribute__((ext_vector_type(4))) float f32x4;
typedef unsigned int u32;

#define BATCH 16
#define CI 512
#define CO 512
#define HW 64
#define SD 512
#define PAD 66   // 64 + 2 halo
#define NCH 16   // channel chunks of 32
#define NK  144  // 16 chunks * 9 taps

// sizes (elements)
#define S_SZ     (BATCH*CI)
#define WSQ_SZ   (CO*CI)
#define WT_SZ    (9*CO*CI)
#define WB_PER_B ((size_t)9*NCH*CO*32)      // shorts
#define XB_PER_B ((size_t)NCH*PAD*PAD*32)   // shorts
#define XROW (PAD*32)
#define XCH  (PAD*PAD*32)

static __device__ __forceinline__ short f2bf(float v) {
    unsigned u = __float_as_uint(v);
    unsigned r = (u + 0x7fffu + ((u >> 16) & 1u)) >> 16;
    return (short)r;
}

static __device__ __forceinline__ void async16(const short* g, short* l) {
    __builtin_amdgcn_global_load_lds(
        (const __attribute__((address_space(1))) u32*)g,
        (__attribute__((address_space(3))) u32*)l, 16, 0, 0);
}

// ---------------- K1: s[b][c] = style[b] . proj_w[c] + proj_b[c] ----------------
__global__ void k_style(const float* __restrict__ style, const float* __restrict__ proj_w,
                        const float* __restrict__ proj_b, float* __restrict__ s) {
    int b = blockIdx.x, cs = blockIdx.y;
    __shared__ float st[SD];
    int t = threadIdx.x;
    for (int d = t; d < SD; d += 256) st[d] = style[b*SD + d];
    __syncthreads();
    int cl = t >> 3, g = t & 7;
    int c = cs*32 + cl;
    const float4* pw4 = reinterpret_cast<const float4*>(proj_w + (size_t)c*SD);
    float sum = 0.f;
    #pragma unroll
    for (int it = 0; it < 16; ++it) {
        float4 v = pw4[g + it*8];
        int d0 = (g + it*8)*4;
        sum += v.x*st[d0] + v.y*st[d0+1] + v.z*st[d0+2] + v.w*st[d0+3];
    }
    sum += __shfl_down(sum, 4);
    sum += __shfl_down(sum, 2);
    sum += __shfl_down(sum, 1);
    if (g == 0) s[b*CI + c] = sum + proj_b[c];
}

// ------------- K2: wsq[o][i] = sum_t w^2 ; wt[t][o][i] = weight[o][i][t] -------------
__global__ void k_wprep(const float* __restrict__ weight, float* __restrict__ wsq,
                        float* __restrict__ wt) {
    int o = blockIdx.x;
    for (int i = threadIdx.x; i < CI; i += 256) {
        const float* wp = weight + ((size_t)o*CI + i)*9;
        float sq = 0.f;
        #pragma unroll
        for (int t = 0; t < 9; ++t) {
            float v = wp[t];
            sq += v*v;
            wt[((size_t)t*CO + o)*CI + i] = v;
        }
        wsq[o*CI + i] = sq;
    }
}

// ------------- K3: demod[b][o] = rsqrt(sum_i s^2 * wsq + 1e-8) -------------
__global__ void k_demod(const float* __restrict__ s, const float* __restrict__ wsq,
                        float* __restrict__ demod) {
    int b = blockIdx.x, os = blockIdx.y;
    __shared__ float s2[CI];
    int t = threadIdx.x;
    for (int d = t; d < CI; d += 256) { float v = s[b*CI + d]; s2[d] = v*v; }
    __syncthreads();
    int ol = t >> 3, g = t & 7;
    int o = os*32 + ol;
    const float4* wq4 = reinterpret_cast<const float4*>(wsq + (size_t)o*CI);
    float sum = 1e-8f;
    #pragma unroll
    for (int it = 0; it < 16; ++it) {
        float4 v = wq4[g + it*8];
        int d0 = (g + it*8)*4;
        sum += v.x*s2[d0] + v.y*s2[d0+1] + v.z*s2[d0+2] + v.w*s2[d0+3];
    }
    sum += __shfl_down(sum, 4);
    sum += __shfl_down(sum, 2);
    sum += __shfl_down(sum, 1);
    if (g == 0) demod[b*CO + o] = rsqrtf(sum);
}

// ------------- K4: wb[b][t][chunk][o][i32] = bf16(wt * s * demod) -------------
__global__ void k_wbfill(const float* __restrict__ wt, const float* __restrict__ s,
                         const float* __restrict__ demod, short* __restrict__ wb) {
    int b = blockIdx.x, t = blockIdx.y, ch = blockIdx.z;
    short* outp = wb + (size_t)b*WB_PER_B + (((size_t)t*NCH + ch)*CO)*32;
    for (int u = threadIdx.x; u < CO*4; u += 256) {
        int o = u >> 2, q = u & 3;
        int i0 = ch*32 + q*8;
        float dm = demod[b*CO + o];
        const float4* wrow = reinterpret_cast<const float4*>(wt + (size_t)t*CO*CI + (size_t)o*CI + i0);
        const float4* srow = reinterpret_cast<const float4*>(s + b*CI + i0);
        float4 w0 = wrow[0], w1 = wrow[1], s0 = srow[0], s1 = srow[1];
        short8 r;
        r[0] = f2bf(w0.x*s0.x*dm); r[1] = f2bf(w0.y*s0.y*dm);
        r[2] = f2bf(w0.z*s0.z*dm); r[3] = f2bf(w0.w*s0.w*dm);
        r[4] = f2bf(w1.x*s1.x*dm); r[5] = f2bf(w1.y*s1.y*dm);
        r[6] = f2bf(w1.z*s1.z*dm); r[7] = f2bf(w1.w*s1.w*dm);
        *reinterpret_cast<short8*>(outp + o*32 + q*8) = r;
    }
}

// ------------- K5: xb[b][chunk][rd][c][ch32] = bf16(x padded), coalesced -------------
__global__ void k_xbfill(const float* __restrict__ x, short* __restrict__ xb) {
    int rd = blockIdx.x;      // dest row 0..65
    int ch = blockIdx.y, b = blockIdx.z;
    int t = threadIdx.x;
    short* rowbase = xb + (size_t)b*XB_PER_B + ((size_t)ch*PAD + rd)*XROW;
    short8 zero = {};
    if (rd == 0 || rd == PAD-1) {
        for (int e = t; e < XROW/8; e += 256)
            *reinterpret_cast<short8*>(rowbase + e*8) = zero;
        return;
    }
    int r = rd - 1;
    __shared__ float tile[32][HW+1];
    int cl = t >> 3, w8 = (t & 7) * 8;
    const float4* src = reinterpret_cast<const float4*>(
        x + (((size_t)(b*CI + ch*32 + cl))*HW + r)*HW + w8);
    float4 v0 = src[0], v1 = src[1];
    tile[cl][w8+0]=v0.x; tile[cl][w8+1]=v0.y; tile[cl][w8+2]=v0.z; tile[cl][w8+3]=v0.w;
    tile[cl][w8+4]=v1.x; tile[cl][w8+5]=v1.y; tile[cl][w8+6]=v1.z; tile[cl][w8+7]=v1.w;
    __syncthreads();
    int w = t >> 2, q = (t & 3) * 8;
    short8 rv;
    #pragma unroll
    for (int j = 0; j < 8; ++j) rv[j] = f2bf(tile[q+j][w]);
    *reinterpret_cast<short8*>(rowbase + (w+1)*32 + q) = rv;
    if (t < 8) {   // zero halo cols 0 and 65
        int px = (t < 4) ? 0 : (PAD-1);
        int qq = (t & 3) * 8;
        *reinterpret_cast<short8*>(rowbase + px*32 + qq) = zero;
    }
}

// ------------- K6: conv as LDS-staged implicit GEMM + T2 XOR swizzle -------------
// block: (b, ot 0..3, pt 0..31); 4 waves 2x2; wave = 64 o x 64 px (one row)
// LDS swizzle: logical (row, 16B-slot) stored at physical slot = slot ^ ((row>>1)&3).
// Write side: linear LDS dest (global_load_lds), pre-swizzled global SOURCE.
// Read side: kb2 = kb ^ ((n16>>1)&3). am*16 row steps don't perturb the XOR.
__global__ __launch_bounds__(256) void k_conv(
        const short* __restrict__ wb, const short* __restrict__ xb,
        const float* __restrict__ noise, const float* __restrict__ noise_strength,
        const float* __restrict__ bias, float* __restrict__ out) {
    __shared__ short abuf[2][128*32];
    __shared__ short bbuf[2][128*32];

    int raw = blockIdx.x;
    int bid = (raw & 7) * 256 + (raw >> 3);   // XCD swizzle (2048 % 8 == 0)
    int b  = bid >> 7;
    int rem = bid & 127;
    int ot = rem >> 5;
    int pt = rem & 31;

    int tid  = threadIdx.x;
    int lane = tid & 63;
    int wid  = tid >> 6;
    int wr = wid >> 1, wc = wid & 1;
    int n16 = lane & 15, kb = lane >> 4;

    int h0 = pt*2;
    int obase_blk = ot*128;
    int obase = obase_blk + wr*64;

    const short* wbase = wb + (size_t)b*WB_PER_B + (size_t)obase_blk*32;
    const short* xbase = xb + (size_t)b*XB_PER_B;

    // staging: wave wid handles A segs {2wid,2wid+1} and B segs {2wid,2wid+1}
    int sa0 = 2*wid;
    int sb0 = 2*wid;
    int lane_dst = lane*8;                                        // physical LDS (shorts)
    int lane_src = (lane>>2)*32 + (((lane&3) ^ ((lane>>3)&3))*8); // swizzled source (shorts)

    f32x4 acc[4][4] = {};

    auto stage = [&](int buf, int ch, int dh, int dw) {
        const short* asrc = wbase + (((size_t)(dh*3+dw)*NCH + ch)*CO)*32;
        async16(asrc +  sa0   *512 + lane_src, &abuf[buf][ sa0   *512 + lane_dst]);
        async16(asrc + (sa0+1)*512 + lane_src, &abuf[buf][(sa0+1)*512 + lane_dst]);
        #pragma unroll
        for (int u = 0; u < 2; ++u) {
            int s = sb0 + u;
            int hr = s >> 2, part = s & 3;
            const short* bsrc = xbase + (size_t)ch*XCH + (size_t)(h0 + hr + dh)*XROW + dw*32;
            async16(bsrc + part*512 + lane_src, &bbuf[buf][s*512 + lane_dst]);
        }
    };

    int ch_n = 0, dh_n = 0, dw_n = 0;
    stage(0, 0, 0, 0);
    dw_n = 1;

    int kb2 = kb ^ ((n16 >> 1) & 3);
    int aoff = (wr*64 + n16)*32 + kb2*8;
    int boff = (wc*64 + n16)*32 + kb2*8;

    for (int kt = 0; kt < NK; ++kt) {
        int cur = kt & 1;
        if (kt + 1 < NK) {
            stage(cur ^ 1, ch_n, dh_n, dw_n);
            if (++dw_n == 3) { dw_n = 0; if (++dh_n == 3) { dh_n = 0; ++ch_n; } }
        }
        __syncthreads();
        const short* A = &abuf[cur][aoff];
        const short* B = &bbuf[cur][boff];
        short8 af[4], bf[4];
        #pragma unroll
        for (int am = 0; am < 4; ++am)
            af[am] = *reinterpret_cast<const short8*>(A + am*16*32);
        #pragma unroll
        for (int an = 0; an < 4; ++an)
            bf[an] = *reinterpret_cast<const short8*>(B + an*16*32);
        #pragma unroll
        for (int am = 0; am < 4; ++am)
            #pragma unroll
            for (int an = 0; an < 4; ++an)
                acc[am][an] = __builtin_amdgcn_mfma_f32_16x16x32_bf16(
                    af[am], bf[an], acc[am][an], 0, 0, 0);
        __syncthreads();
    }

    // epilogue: + noise*strength + bias
    int h = h0 + wc;
    float ns0 = noise_strength[0];
    const float* nz = noise + b*HW*HW + h*HW + n16;
    float* ob = out + ((size_t)b*CO + obase)*HW*HW + h*HW + n16;
    #pragma unroll
    for (int an = 0; an < 4; ++an) {
        float nv = nz[an*16] * ns0;
        #pragma unroll
        for (int am = 0; am < 4; ++am) {
            int o_lo = am*16 + kb*4;
            #pragma unroll
            for (int j = 0; j < 4; ++j) {
                float bv = bias[obase + o_lo + j];
                ob[(size_t)(o_lo + j)*(HW*HW) + an*16] = acc[am][an][j] + nv + bv;
            }
        }
    }
}

extern "C" void kernel_launch(void* const* d_in, const int* in_sizes, int n_in,
                              void* d_out, int out_size, void* d_ws, size_t ws_size,
                              hipStream_t stream) {
    const float* x        = (const float*)d_in[0];
    const float* style    = (const float*)d_in[1];
    const float* noise    = (const float*)d_in[2];
    const float* weight   = (const float*)d_in[3];
    const float* proj_w   = (const float*)d_in[4];
    const float* proj_b   = (const float*)d_in[5];
    const float* noise_st = (const float*)d_in[6];
    const float* bias     = (const float*)d_in[7];
    float* out = (float*)d_out;

    float* s     = (float*)d_ws;
    float* demod = s + S_SZ;
    float* wsq   = demod + S_SZ;
    float* wt    = wsq + WSQ_SZ;
    short* wbuf  = (short*)(wt + WT_SZ);
    short* xbuf  = wbuf + BATCH*WB_PER_B;

    k_style<<<dim3(BATCH, 16), 256, 0, stream>>>(style, proj_w, proj_b, s);
    k_wprep<<<CO, 256, 0, stream>>>(weight, wsq, wt);
    k_demod<<<dim3(BATCH, 16), 256, 0, stream>>>(s, wsq, demod);
    k_wbfill<<<dim3(BATCH, 9, NCH), 256, 0, stream>>>(wt, s, demod, wbuf);
    k_xbfill<<<dim3(PAD, NCH, BATCH), 256, 0, stream>>>(x, xbuf);
    k_conv<<<2048, 256, 0, stream>>>(wbuf, xbuf, noise, noise_st, bias, out);
}